// Round 7
// baseline (526.397 us; speedup 1.0000x reference)
//
#include <hip/hip_runtime.h>

// Problem constants
#define NPOS 32768          // B*H*W = 32*32*32
#define DDIM 256
#define KCODE 1024
#define HW 1024             // H*W
#define BSTRIDE (256*1024)  // D*H*W per batch element
#define OUT0_SIZE 8388608   // B*D*H*W
#define OUT1_SIZE 32768

// ws layout (4-byte units):
//  [0 .. 262143]        ET    : transposed codebook [d][k]        (float)
//  [262144 .. 327679]   zn2   : per-position pairwise HALVES      (float, 2*32768)
//  [327680 .. 328703]   en    : ||e_k||^2 numpy-pairwise f32      (float, 1024)
//  [328704 .. 394239]   packed: (f32bits(d)<<32)|k per pos        (u64, 32768)
#define WS_ET     0
#define WS_ZN2    262144
#define WS_EN     327680
#define WS_PACKED 328704   // *4 bytes is 8-aligned

// ---------------------------------------------------------------------------
// K1: fused prep. grid 324 blocks x 256 threads:
//   [0,256)   : zn halves (numpy pairwise 128-blocks) + packed init (+loss 0)
//   [256,260) : en[k] numpy-pairwise
//   [260,324) : 64x64 LDS-tiled transpose cb -> ET
__global__ void vq_prep(const float* __restrict__ z,
                        const float* __restrict__ cb,
                        float* __restrict__ ws_f,
                        unsigned long long* __restrict__ packed,
                        float* __restrict__ loss_slot) {
    __shared__ float tile[64][65];
    int bx = blockIdx.x;
    int t  = threadIdx.x;

    if (bx < 256) {                       // ---- zn-half role
        int p = t >> 1, h = t & 1;
        int n = bx * 128 + p;
        int b = n >> 10, hw = n & 1023;
        const float* base = z + (size_t)b * BSTRIDE + hw + (size_t)(h * 128) * HW;
        float r[8];
        #pragma unroll
        for (int j = 0; j < 8; ++j) {
            float v = base[(size_t)j * HW];
            r[j] = __fmul_rn(v, v);
        }
        #pragma unroll
        for (int i = 8; i < 128; i += 8) {
            #pragma unroll
            for (int j = 0; j < 8; ++j) {
                float v = base[(size_t)(i + j) * HW];
                r[j] = __fadd_rn(r[j], __fmul_rn(v, v));
            }
        }
        float half_s = __fadd_rn(
            __fadd_rn(__fadd_rn(r[0], r[1]), __fadd_rn(r[2], r[3])),
            __fadd_rn(__fadd_rn(r[4], r[5]), __fadd_rn(r[6], r[7])));
        ws_f[WS_ZN2 + 2 * n + h] = half_s;
        if (h == 0) packed[n] = 0xFFFFFFFFFFFFFFFFull;
        if (bx == 0 && t == 0) *loss_slot = 0.0f;
    } else if (bx < 260) {                // ---- en role
        int k = (bx - 256) * 256 + t;
        const float* row = cb + (size_t)k * DDIM;
        float half_s[2];
        #pragma unroll
        for (int h = 0; h < 2; ++h) {
            const float* p2 = row + h * 128;
            float r[8];
            #pragma unroll
            for (int j = 0; j < 8; ++j) r[j] = __fmul_rn(p2[j], p2[j]);
            #pragma unroll
            for (int i = 8; i < 128; i += 8) {
                #pragma unroll
                for (int j = 0; j < 8; ++j)
                    r[j] = __fadd_rn(r[j], __fmul_rn(p2[i + j], p2[i + j]));
            }
            half_s[h] = __fadd_rn(
                __fadd_rn(__fadd_rn(r[0], r[1]), __fadd_rn(r[2], r[3])),
                __fadd_rn(__fadd_rn(r[4], r[5]), __fadd_rn(r[6], r[7])));
        }
        ws_f[WS_EN + k] = __fadd_rn(half_s[0], half_s[1]);
    } else {                              // ---- transpose role
        int bt = bx - 260;
        int k0 = (bt & 15) * 64;
        int d0 = (bt >> 4) * 64;
        float* et = ws_f + WS_ET;
        #pragma unroll
        for (int p = 0; p < 4; ++p) {
            int r  = p * 16 + (t >> 4);
            int c4 = (t & 15) * 4;
            float4 v = *reinterpret_cast<const float4*>(
                cb + (size_t)(k0 + r) * DDIM + d0 + c4);
            tile[r][c4] = v.x; tile[r][c4+1] = v.y;
            tile[r][c4+2] = v.z; tile[r][c4+3] = v.w;
        }
        __syncthreads();
        #pragma unroll
        for (int s = 0; s < 16; ++s) {
            int dd = s * 4 + (t >> 6);
            int kk = t & 63;
            et[(size_t)(d0 + dd) * KCODE + k0 + kk] = tile[kk][dd];
        }
    }
}

// ---------------------------------------------------------------------------
// K2: distance-GEMM + argmin.
//
// R14 = R12 + ONE change: B double-buffer with register prefetch (T14
// issue-early / write-late). R12's counters: VALUBusy 66%, ~3.2 us/tile of
// staging-serialization stall (stage -> barrier -> compute -> barrier, all
// waves lockstepped). R12's footprint (VGPR 48, acc 64) finally affords
// the 8 VGPRs of staging registers that R9/R10 could not (they spilled at
// acc=128). Schedule per tile: issue tile t+1's TWO float4 global loads ->
// compute tile t (2048 cy/wave hides the latency) -> ds_write to the
// alternate Bs buffer -> ONE barrier. Race-free: buffer cur^1 was released
// by the barrier at the end of tile t-1.
// A-path unchanged from R12 (wave-uniform s_load via readfirstlane'd wave
// id; SMEM, zero LDS traffic, 1-SGPR operand of v_fmac). BK=16 unchanged
// (R13's BK=32 + per-lane-VMEM-A regressed 223->343; reverted).
// Layout: wave owns 16 positions, lane owns 4 codes (kc+4*lane..+3).
// Per-(n,k) FMA chain (d=0..255 ascending, sequential fmaf,
// fl(fl(zn+en)-fl(2*dot))) UNCHANGED -> bit-identical distances; tie-break
// order preserved. Cross-block merge: atomicMin on (f32bits(d)<<32)|k.
#define BM 128
#define BN 256
#define BK 16

__launch_bounds__(512, 4)
__global__ void vq_argmin(const float* __restrict__ z,
                          const float* __restrict__ ws_f,
                          unsigned long long* __restrict__ packed) {
    __shared__ float Bs[2][BK][BN];  // [buf][dk][code] 2 x 16 KB

    const float* ET  = ws_f + WS_ET;
    const float* zn2 = ws_f + WS_ZN2;
    const float* enW = ws_f + WS_EN;

    int t    = threadIdx.x;
    int lane = t & 63;
    int wq   = __builtin_amdgcn_readfirstlane(t >> 6);   // wave id 0..7 (SGPR)
    int bc = blockIdx.x & 3;         // code-range quarter
    int bm = blockIdx.x >> 2;
    int kc = bc * BN;
    int n0 = bm * BM;                // 128 | 1024 -> single batch row
    int b  = n0 >> 10, hw0 = n0 & 1023;
    const float* zb = z + (size_t)b * BSTRIDE + hw0;
    const float* za = zb + wq * 16;  // wave-uniform A base (16 positions)

    // staging coordinates: f4 index f = t (i=0) and t+512 (i=1):
    //   row dk = (f>>6) = dkS + 8*i, col group m = f&63
    const int dkS = t >> 6;          // 0..7
    const int mS  = t & 63;
    const float* gB = ET + (size_t)dkS * KCODE + kc + 4 * mS;  // + d*KCODE

    float acc[16][4];
    #pragma unroll
    for (int j = 0; j < 16; ++j)
        #pragma unroll
        for (int c = 0; c < 4; ++c) acc[j][c] = 0.0f;

    // ---- prologue: stage tile 0 into buffer 0, one barrier
    float4 rb0 = *reinterpret_cast<const float4*>(gB);
    float4 rb1 = *reinterpret_cast<const float4*>(gB + (size_t)8 * KCODE);
    *reinterpret_cast<float4*>(&Bs[0][dkS][4 * mS])     = rb0;
    *reinterpret_cast<float4*>(&Bs[0][dkS + 8][4 * mS]) = rb1;
    __syncthreads();

    for (int tt = 0; tt < 16; ++tt) {
        const int cur = tt & 1;

        // issue next tile's loads BEFORE compute (latency hides under FMA)
        if (tt < 15) {
            const float* gBn = gB + (size_t)((tt + 1) * BK) * KCODE;
            rb0 = *reinterpret_cast<const float4*>(gBn);
            rb1 = *reinterpret_cast<const float4*>(gBn + (size_t)8 * KCODE);
        }

        // compute on buf[cur] — FMA order identical to verified kernel
        const int d0 = tt * BK;
        #pragma unroll
        for (int dk = 0; dk < BK; ++dk) {
            float4 b4 = *reinterpret_cast<const float4*>(&Bs[cur][dk][4 * lane]);
            const float* ar = za + (size_t)(d0 + dk) * HW;   // uniform addr
            float4 a0 = *reinterpret_cast<const float4*>(ar);
            float4 a1 = *reinterpret_cast<const float4*>(ar + 4);
            float4 a2 = *reinterpret_cast<const float4*>(ar + 8);
            float4 a3 = *reinterpret_cast<const float4*>(ar + 12);
            float a[16] = {a0.x, a0.y, a0.z, a0.w, a1.x, a1.y, a1.z, a1.w,
                           a2.x, a2.y, a2.z, a2.w, a3.x, a3.y, a3.z, a3.w};
            float bb[4] = {b4.x, b4.y, b4.z, b4.w};
            #pragma unroll
            for (int j = 0; j < 16; ++j)
                #pragma unroll
                for (int c = 0; c < 4; ++c)
                    acc[j][c] = fmaf(a[j], bb[c], acc[j][c]);
        }

        // write prefetched tile to the other buffer; ONE barrier per tile
        if (tt < 15) {
            const int nxt = cur ^ 1;
            *reinterpret_cast<float4*>(&Bs[nxt][dkS][4 * mS])     = rb0;
            *reinterpret_cast<float4*>(&Bs[nxt][dkS + 8][4 * mS]) = rb1;
            __syncthreads();
        }
    }

    // epilogue: d = fl(fl(zn+en) - fl(2*dot)); strict < keeps first index.
    // lane owns codes kc+4*lane+c (c asc = k asc).
    float4 e4 = *reinterpret_cast<const float4*>(enW + kc + 4 * lane);
    float en4[4] = {e4.x, e4.y, e4.z, e4.w};

    #pragma unroll
    for (int j = 0; j < 16; ++j) {
        int n = n0 + wq * 16 + j;
        float znr = __fadd_rn(zn2[2 * n], zn2[2 * n + 1]);
        float m1 = 1e30f;
        int   i1 = 0;
        #pragma unroll
        for (int c = 0; c < 4; ++c) {
            int k = kc + 4 * lane + c;
            float t1 = __fadd_rn(znr, en4[c]);
            float d  = __fsub_rn(t1, __fmul_rn(2.0f, acc[j][c]));
            if (d < m1) { m1 = d; i1 = k; }
        }
        // 64-lane butterfly argmin (smaller index wins ties)
        #pragma unroll
        for (int off = 1; off < 64; off <<= 1) {
            float o1 = __shfl_xor(m1, off, 64);
            int   oi = __shfl_xor(i1, off, 64);
            if (o1 < m1 || (o1 == m1 && oi < i1)) { m1 = o1; i1 = oi; }
        }
        if (lane == 0) {
            unsigned long long key =
                ((unsigned long long)__float_as_uint(m1) << 32) |
                (unsigned long long)(unsigned)i1;
            atomicMin(&packed[n], key);
        }
    }
}

// ---------------------------------------------------------------------------
// K3: index extract + gather zq + transpose to (B,D,H,W) + loss.
// grid 512 blocks x 256 threads: block = 64 positions x 4 d-chunks of 64.
__global__ void vq_gather(const float* __restrict__ z,
                          const float* __restrict__ cb,
                          const unsigned long long* __restrict__ packed,
                          float* __restrict__ out,
                          float* __restrict__ loss) {
    int t  = threadIdx.x;
    int p  = t & 63, dc = t >> 6;
    int n  = blockIdx.x * 64 + p;
    int b  = n >> 10, hw = n & 1023;
    int k  = (int)(unsigned)(packed[n] & 0xFFFFFFFFull);
    size_t off = (size_t)b * BSTRIDE + hw + (size_t)(dc * 64) * HW;
    const float* e  = cb + (size_t)k * DDIM + dc * 64;
    const float* zp = z + off;
    float* op = out + off;
    float s = 0.0f;
    #pragma unroll 4
    for (int d4 = 0; d4 < 16; ++d4) {
        float4 ev = *reinterpret_cast<const float4*>(e + 4 * d4);
        float evs[4] = {ev.x, ev.y, ev.z, ev.w};
        #pragma unroll
        for (int q = 0; q < 4; ++q) {
            int d = 4 * d4 + q;
            float zv = zp[(size_t)d * HW];
            op[(size_t)d * HW] = evs[q];
            float df = evs[q] - zv;
            s = fmaf(df, df, s);
        }
    }
    if (dc == 0) out[OUT0_SIZE + n] = (float)k;

    #pragma unroll
    for (int o = 32; o > 0; o >>= 1) s += __shfl_down(s, o);
    __shared__ float red[4];
    int lane = t & 63, w = t >> 6;
    if (lane == 0) red[w] = s;
    __syncthreads();
    if (t == 0) {
        float tot = (red[0] + red[1] + red[2] + red[3]) * (2.0f / 8388608.0f);
        atomicAdd(loss, tot);
    }
}

// ---------------------------------------------------------------------------
extern "C" void kernel_launch(void* const* d_in, const int* in_sizes, int n_in,
                              void* d_out, int out_size, void* d_ws, size_t ws_size,
                              hipStream_t stream) {
    const float* z  = (const float*)d_in[0];
    const float* cb = (const float*)d_in[1];
    float* out  = (float*)d_out;
    float* ws_f = (float*)d_ws;
    unsigned long long* packed =
        (unsigned long long*)(ws_f + WS_PACKED);
    float* loss = out + OUT0_SIZE + OUT1_SIZE;

    vq_prep<<<324, 256, 0, stream>>>(z, cb, ws_f, packed, loss);
    vq_argmin<<<(NPOS / BM) * (KCODE / BN), 512, 0, stream>>>(z, ws_f, packed);
    vq_gather<<<NPOS / 64, 256, 0, stream>>>(z, cb, packed, out, loss);
}

// Round 8
// 346.215 us; speedup vs baseline: 1.5204x; 1.5204x over previous
//
#include <hip/hip_runtime.h>

// Problem constants
#define NPOS 32768          // B*H*W = 32*32*32
#define DDIM 256
#define KCODE 1024
#define HW 1024             // H*W
#define BSTRIDE (256*1024)  // D*H*W per batch element
#define OUT0_SIZE 8388608   // B*D*H*W
#define OUT1_SIZE 32768

// ws layout (4-byte units):
//  [0 .. 262143]        ET    : transposed codebook [d][k]        (float)
//  [262144 .. 327679]   zn2   : per-position pairwise HALVES      (float, 2*32768)
//  [327680 .. 328703]   en    : ||e_k||^2 numpy-pairwise f32      (float, 1024)
//  [328704 .. 394239]   packed: (f32bits(d)<<32)|k per pos        (u64, 32768)
#define WS_ET     0
#define WS_ZN2    262144
#define WS_EN     327680
#define WS_PACKED 328704   // *4 bytes is 8-aligned

typedef __attribute__((ext_vector_type(2))) float f32x2;

// ---------------------------------------------------------------------------
// K1: fused prep. grid 324 blocks x 256 threads:
//   [0,256)   : zn halves (numpy pairwise 128-blocks) + packed init (+loss 0)
//   [256,260) : en[k] numpy-pairwise
//   [260,324) : 64x64 LDS-tiled transpose cb -> ET
__global__ void vq_prep(const float* __restrict__ z,
                        const float* __restrict__ cb,
                        float* __restrict__ ws_f,
                        unsigned long long* __restrict__ packed,
                        float* __restrict__ loss_slot) {
    __shared__ float tile[64][65];
    int bx = blockIdx.x;
    int t  = threadIdx.x;

    if (bx < 256) {                       // ---- zn-half role
        int p = t >> 1, h = t & 1;
        int n = bx * 128 + p;
        int b = n >> 10, hw = n & 1023;
        const float* base = z + (size_t)b * BSTRIDE + hw + (size_t)(h * 128) * HW;
        float r[8];
        #pragma unroll
        for (int j = 0; j < 8; ++j) {
            float v = base[(size_t)j * HW];
            r[j] = __fmul_rn(v, v);
        }
        #pragma unroll
        for (int i = 8; i < 128; i += 8) {
            #pragma unroll
            for (int j = 0; j < 8; ++j) {
                float v = base[(size_t)(i + j) * HW];
                r[j] = __fadd_rn(r[j], __fmul_rn(v, v));
            }
        }
        float half_s = __fadd_rn(
            __fadd_rn(__fadd_rn(r[0], r[1]), __fadd_rn(r[2], r[3])),
            __fadd_rn(__fadd_rn(r[4], r[5]), __fadd_rn(r[6], r[7])));
        ws_f[WS_ZN2 + 2 * n + h] = half_s;
        if (h == 0) packed[n] = 0xFFFFFFFFFFFFFFFFull;
        if (bx == 0 && t == 0) *loss_slot = 0.0f;
    } else if (bx < 260) {                // ---- en role
        int k = (bx - 256) * 256 + t;
        const float* row = cb + (size_t)k * DDIM;
        float half_s[2];
        #pragma unroll
        for (int h = 0; h < 2; ++h) {
            const float* p2 = row + h * 128;
            float r[8];
            #pragma unroll
            for (int j = 0; j < 8; ++j) r[j] = __fmul_rn(p2[j], p2[j]);
            #pragma unroll
            for (int i = 8; i < 128; i += 8) {
                #pragma unroll
                for (int j = 0; j < 8; ++j)
                    r[j] = __fadd_rn(r[j], __fmul_rn(p2[i + j], p2[i + j]));
            }
            half_s[h] = __fadd_rn(
                __fadd_rn(__fadd_rn(r[0], r[1]), __fadd_rn(r[2], r[3])),
                __fadd_rn(__fadd_rn(r[4], r[5]), __fadd_rn(r[6], r[7])));
        }
        ws_f[WS_EN + k] = __fadd_rn(half_s[0], half_s[1]);
    } else {                              // ---- transpose role
        int bt = bx - 260;
        int k0 = (bt & 15) * 64;
        int d0 = (bt >> 4) * 64;
        float* et = ws_f + WS_ET;
        #pragma unroll
        for (int p = 0; p < 4; ++p) {
            int r  = p * 16 + (t >> 4);
            int c4 = (t & 15) * 4;
            float4 v = *reinterpret_cast<const float4*>(
                cb + (size_t)(k0 + r) * DDIM + d0 + c4);
            tile[r][c4] = v.x; tile[r][c4+1] = v.y;
            tile[r][c4+2] = v.z; tile[r][c4+3] = v.w;
        }
        __syncthreads();
        #pragma unroll
        for (int s = 0; s < 16; ++s) {
            int dd = s * 4 + (t >> 6);
            int kk = t & 63;
            et[(size_t)(d0 + dd) * KCODE + k0 + kk] = tile[kk][dd];
        }
    }
}

// ---------------------------------------------------------------------------
// K2: distance-GEMM + argmin.
//
// R15 = R12 structure (verified 224 us: single-buffered Bs, two barriers
// per K-tile, wave-uniform A via SMEM, lane owns 4 codes) + ONE change:
// the inner loop issues v_pk_fma_f32 (VOP3P packed f32) pairing POSITIONS
// (j,j+1). Each packed half is an IEEE fp32 fma -> per-(n,k) chain is
// bit-identical to fmaf d=0..255 ascending. The A-pair (a[2p],a[2p+1])
// comes free as an even-aligned SGPR pair out of the existing
// s_load_dwordx4 (uniform address), passed via "s" constraint (one scalar
// operand per VALU instr: OK). Only B needs dup: 4 x 2 v_mov per dk.
// Per-dk VALU issue: 64 FMA (128 cy) -> 32 pk_fma + 8 mov (80 cy), 1.6x
// less issue in the hot loop. NO new live state across the loop (acc2 is
// the same 64 VGPRs as acc was) -> no spill vector. All pipelining
// attempts (R9/R10/R14) spilled to scratch; schedule stays R12's.
// Tie-break order preserved (c asc = k asc within lane, smaller k wins
// across lanes/blocks). Cross-block merge: atomicMin on (f32bits(d)<<32)|k.
#define BM 128
#define BN 256
#define BK 16

__launch_bounds__(512, 4)
__global__ void vq_argmin(const float* __restrict__ z,
                          const float* __restrict__ ws_f,
                          unsigned long long* __restrict__ packed) {
    __shared__ float Bs[BK][BN];     // [dk][code] 16 KB

    const float* ET  = ws_f + WS_ET;
    const float* zn2 = ws_f + WS_ZN2;
    const float* enW = ws_f + WS_EN;

    int t    = threadIdx.x;
    int lane = t & 63;
    int wq   = __builtin_amdgcn_readfirstlane(t >> 6);   // wave id 0..7 (SGPR)
    int bc = blockIdx.x & 3;         // code-range quarter
    int bm = blockIdx.x >> 2;
    int kc = bc * BN;
    int n0 = bm * BM;                // 128 | 1024 -> single batch row
    int b  = n0 >> 10, hw0 = n0 & 1023;
    const float* zb = z + (size_t)b * BSTRIDE + hw0;
    const float* za = zb + wq * 16;  // wave-uniform A base (16 positions)

    // acc2[p][c]: lo half = position 2p, hi half = position 2p+1, code c
    f32x2 acc2[8][4];
    #pragma unroll
    for (int p = 0; p < 8; ++p)
        #pragma unroll
        for (int c = 0; c < 4; ++c) acc2[p][c] = (f32x2){0.0f, 0.0f};

    for (int d0 = 0; d0 < DDIM; d0 += BK) {
        __syncthreads();
        #pragma unroll
        for (int i = 0; i < 2; ++i) {   // stage B: 16x256 floats, linear
            int q = t + i * 512;
            int dk = q >> 6, m = q & 63;          // codes 4m..4m+3
            float4 v = *reinterpret_cast<const float4*>(
                ET + (size_t)(d0 + dk) * KCODE + kc + 4 * m);
            *reinterpret_cast<float4*>(&Bs[dk][4 * m]) = v;
        }
        __syncthreads();

        #pragma unroll
        for (int dk = 0; dk < BK; ++dk) {
            float4 b4 = *reinterpret_cast<const float4*>(&Bs[dk][4 * lane]);
            const float* ar = za + (size_t)(d0 + dk) * HW;   // uniform addr
            float4 a0 = *reinterpret_cast<const float4*>(ar);
            float4 a1 = *reinterpret_cast<const float4*>(ar + 4);
            float4 a2 = *reinterpret_cast<const float4*>(ar + 8);
            float4 a3 = *reinterpret_cast<const float4*>(ar + 12);
            // position pairs: even-aligned SGPR pairs straight from the
            // s_load_dwordx4 results (no dup needed)
            f32x2 ap[8] = {{a0.x, a0.y}, {a0.z, a0.w},
                           {a1.x, a1.y}, {a1.z, a1.w},
                           {a2.x, a2.y}, {a2.z, a2.w},
                           {a3.x, a3.y}, {a3.z, a3.w}};
            // code broadcast pairs (8 v_mov)
            f32x2 bd[4] = {{b4.x, b4.x}, {b4.y, b4.y},
                           {b4.z, b4.z}, {b4.w, b4.w}};
            #pragma unroll
            for (int p = 0; p < 8; ++p)
                #pragma unroll
                for (int c = 0; c < 4; ++c)
                    asm("v_pk_fma_f32 %0, %1, %2, %0"
                        : "+v"(acc2[p][c])
                        : "s"(ap[p]), "v"(bd[c]));
        }
    }

    // epilogue: d = fl(fl(zn+en) - fl(2*dot)); strict < keeps first index.
    // lane owns codes kc+4*lane+c (c asc = k asc).
    float4 e4 = *reinterpret_cast<const float4*>(enW + kc + 4 * lane);
    float en4[4] = {e4.x, e4.y, e4.z, e4.w};

    #pragma unroll
    for (int j = 0; j < 16; ++j) {
        int n = n0 + wq * 16 + j;
        float znr = __fadd_rn(zn2[2 * n], zn2[2 * n + 1]);
        float m1 = 1e30f;
        int   i1 = 0;
        #pragma unroll
        for (int c = 0; c < 4; ++c) {
            int k = kc + 4 * lane + c;
            float dot = (j & 1) ? acc2[j >> 1][c][1] : acc2[j >> 1][c][0];
            float t1 = __fadd_rn(znr, en4[c]);
            float d  = __fsub_rn(t1, __fmul_rn(2.0f, dot));
            if (d < m1) { m1 = d; i1 = k; }
        }
        // 64-lane butterfly argmin (smaller index wins ties)
        #pragma unroll
        for (int off = 1; off < 64; off <<= 1) {
            float o1 = __shfl_xor(m1, off, 64);
            int   oi = __shfl_xor(i1, off, 64);
            if (o1 < m1 || (o1 == m1 && oi < i1)) { m1 = o1; i1 = oi; }
        }
        if (lane == 0) {
            unsigned long long key =
                ((unsigned long long)__float_as_uint(m1) << 32) |
                (unsigned long long)(unsigned)i1;
            atomicMin(&packed[n], key);
        }
    }
}

// ---------------------------------------------------------------------------
// K3: index extract + gather zq + transpose to (B,D,H,W) + loss.
// grid 512 blocks x 256 threads: block = 64 positions x 4 d-chunks of 64.
__global__ void vq_gather(const float* __restrict__ z,
                          const float* __restrict__ cb,
                          const unsigned long long* __restrict__ packed,
                          float* __restrict__ out,
                          float* __restrict__ loss) {
    int t  = threadIdx.x;
    int p  = t & 63, dc = t >> 6;
    int n  = blockIdx.x * 64 + p;
    int b  = n >> 10, hw = n & 1023;
    int k  = (int)(unsigned)(packed[n] & 0xFFFFFFFFull);
    size_t off = (size_t)b * BSTRIDE + hw + (size_t)(dc * 64) * HW;
    const float* e  = cb + (size_t)k * DDIM + dc * 64;
    const float* zp = z + off;
    float* op = out + off;
    float s = 0.0f;
    #pragma unroll 4
    for (int d4 = 0; d4 < 16; ++d4) {
        float4 ev = *reinterpret_cast<const float4*>(e + 4 * d4);
        float evs[4] = {ev.x, ev.y, ev.z, ev.w};
        #pragma unroll
        for (int q = 0; q < 4; ++q) {
            int d = 4 * d4 + q;
            float zv = zp[(size_t)d * HW];
            op[(size_t)d * HW] = evs[q];
            float df = evs[q] - zv;
            s = fmaf(df, df, s);
        }
    }
    if (dc == 0) out[OUT0_SIZE + n] = (float)k;

    #pragma unroll
    for (int o = 32; o > 0; o >>= 1) s += __shfl_down(s, o);
    __shared__ float red[4];
    int lane = t & 63, w = t >> 6;
    if (lane == 0) red[w] = s;
    __syncthreads();
    if (t == 0) {
        float tot = (red[0] + red[1] + red[2] + red[3]) * (2.0f / 8388608.0f);
        atomicAdd(loss, tot);
    }
}

// ---------------------------------------------------------------------------
extern "C" void kernel_launch(void* const* d_in, const int* in_sizes, int n_in,
                              void* d_out, int out_size, void* d_ws, size_t ws_size,
                              hipStream_t stream) {
    const float* z  = (const float*)d_in[0];
    const float* cb = (const float*)d_in[1];
    float* out  = (float*)d_out;
    float* ws_f = (float*)d_ws;
    unsigned long long* packed =
        (unsigned long long*)(ws_f + WS_PACKED);
    float* loss = out + OUT0_SIZE + OUT1_SIZE;

    vq_prep<<<324, 256, 0, stream>>>(z, cb, ws_f, packed, loss);
    vq_argmin<<<(NPOS / BM) * (KCODE / BN), 512, 0, stream>>>(z, ws_f, packed);
    vq_gather<<<NPOS / 64, 256, 0, stream>>>(z, cb, packed, out, loss);
}